// Round 22
// baseline (199.943 us; speedup 1.0000x reference)
//
#include <hip/hip_runtime.h>
#include <stdint.h>

// PointNet SA via MFMA, v17 = v13 (best, 183us) + ASM-PINNED weight prefetch.
// v13/v16 both failed to hoist weight loads (VGPR stayed 52 = loads re-sunk
// into the MFMA chain; sched_barrier(0) doesn't stop machine-sinking). The
// rule-17 idiom asm volatile("" :: "v"(x)) creates a hard use: loads MUST
// complete before the pin. Stage-g weights preload before the gather (latency
// hides under gather+barrier); s1/s2/s3 pin their weight cluster at stage top.

namespace {
constexpr int kB = 4, kN = 16384, kC = 103, kP = 2048, kS = 32;

using short8 = __attribute__((ext_vector_type(8))) short;
using short4 = __attribute__((ext_vector_type(4))) short;
using f32x4  = __attribute__((ext_vector_type(4))) float;

constexpr int WG_HI = 0,     WG_LO = 8192;     // 64 x 128
constexpr int W1_HI = 16384, W1_LO = 20480;    // 64 x 64
constexpr int W2_HI = 24576, W2_LO = 32768;    // 128 x 64
constexpr int W3_HI = 40960, W3_LO = 73728;    // 256 x 128
constexpr size_t FT_OFF    = 262144;
constexpr size_t FT_SHORTS = (size_t)kB * kN * 128;
constexpr size_t WS_NEED   = FT_OFF + 2 * FT_SHORTS * 2;

__device__ __forceinline__ unsigned short f2bf(float x) {
    unsigned u = __float_as_uint(x);
    u += 0x7fffu + ((u >> 16) & 1u);           // RNE
    return (unsigned short)(u >> 16);
}
__device__ __forceinline__ float bf2f(unsigned short h) {
    return __uint_as_float((unsigned)h << 16);
}
__device__ __forceinline__ unsigned cvtpk(float a, float b) {
    unsigned r;
    asm("v_cvt_pk_bf16_f32 %0, %1, %2" : "=v"(r) : "v"(a), "v"(b));
    return r;
}
__device__ __forceinline__ void pack4(const float v[4], uint2& H, uint2& L) {
    H.x = cvtpk(v[0], v[1]);
    H.y = cvtpk(v[2], v[3]);
    const float r0 = v[0] - __uint_as_float(H.x << 16);
    const float r1 = v[1] - __uint_as_float(H.x & 0xffff0000u);
    const float r2 = v[2] - __uint_as_float(H.y << 16);
    const float r3 = v[3] - __uint_as_float(H.y & 0xffff0000u);
    L.x = cvtpk(r0, r1);
    L.y = cvtpk(r2, r3);
}
__device__ __forceinline__ f32x4 mfma3(short8 ah, short8 al, short8 bh, short8 bl, f32x4 acc) {
    acc = __builtin_amdgcn_mfma_f32_16x16x32_bf16(ah, bh, acc, 0, 0, 0);
    acc = __builtin_amdgcn_mfma_f32_16x16x32_bf16(ah, bl, acc, 0, 0, 0);
    acc = __builtin_amdgcn_mfma_f32_16x16x32_bf16(al, bh, acc, 0, 0, 0);
    return acc;
}
// rule-17 pin: hard use -> the producing load cannot sink below this point
__device__ __forceinline__ void pin(short8 v) {
    asm volatile("" :: "v"(v));
}

__global__ void copy_newxyz(const float* __restrict__ src, float* __restrict__ dst, int n) {
    int i = blockIdx.x * blockDim.x + threadIdx.x;
    if (i < n) dst[i] = src[i];
}

__global__ void prep_weights(const float* __restrict__ Wg, const float* __restrict__ W1,
                             const float* __restrict__ W2, const float* __restrict__ W3,
                             short* __restrict__ ws) {
    int i = blockIdx.x * blockDim.x + threadIdx.x;
    if (i >= 53248) return;
    float w; int hi, lo, j;
    if (i < 8192)       { j = i;         int o = j >> 7, c = j & 127; w = (c < 106) ? Wg[o * 106 + c] : 0.f; hi = WG_HI; lo = WG_LO; }
    else if (i < 12288) { j = i - 8192;  int o = j >> 6, c = j & 63;  w = W1[o * 64 + c];  hi = W1_HI; lo = W1_LO; }
    else if (i < 20480) { j = i - 12288; int o = j >> 6, c = j & 63;  w = W2[o * 64 + c];  hi = W2_HI; lo = W2_LO; }
    else                { j = i - 20480; int o = j >> 7, c = j & 127; w = W3[o * 128 + c]; hi = W3_HI; lo = W3_LO; }
    unsigned short h = f2bf(w);
    ws[hi + j] = (short)h;
    ws[lo + j] = (short)f2bf(w - bf2f(h));
}

__global__ __launch_bounds__(512) void prep_feat(const float* __restrict__ f,
                                                 short* __restrict__ ftH, short* __restrict__ ftL) {
    __shared__ float tile[kC][65];
    const int bb = blockIdx.x >> 8;
    const int n0 = (blockIdx.x & 255) * 64;
    const int tid = threadIdx.x;
    for (int c = tid >> 6; c < kC; c += 8)
        tile[c][tid & 63] = f[((size_t)bb * kC + c) * kN + n0 + (tid & 63)];
    __syncthreads();
    const int np = tid >> 3, gc = tid & 7;
    short* rH = ftH + ((size_t)bb * kN + n0 + np) * 128;
    short* rL = ftL + ((size_t)bb * kN + n0 + np) * 128;
    #pragma unroll
    for (int kk = 0; kk < 2; ++kk) {
        const int chunk = gc + 8 * kk;
        union { uint4 u; short s[8]; } H, L;
        #pragma unroll
        for (int e = 0; e < 8; ++e) {
            const int col = chunk * 8 + e;
            float v = (col >= 3 && col < 106) ? tile[col - 3][np] : 0.f;
            unsigned short hh = f2bf(v);
            H.s[e] = (short)hh;
            L.s[e] = (short)f2bf(v - bf2f(hh));
        }
        *(uint4*)(rH + chunk * 8) = H.u;
        *(uint4*)(rL + chunk * 8) = L.u;
    }
}

// A: m=lane&15 (W row), k=8*(lane>>4)+j; B: n=lane&15 (point), same k; D: n=lane&15, m=4*(lane>>4)+r
// Weight cluster loaded + PINNED at stage top; then ds_read+MFMA chain.
template<int NOT, int NPT, int KT, int LDC, int LDW, bool INIT>
__device__ __forceinline__ void gemm_core(
    const short* __restrict__ xh, const short* __restrict__ xl,
    const short* __restrict__ wh, const short* __restrict__ wl,
    const float* __restrict__ bias, int kwoff,
    int ot0, int pt0t, int lane, f32x4 (&acc)[NOT][NPT])
{
    const int q = lane >> 4, n16 = lane & 15;
    short8 whr[NOT * KT], wlr[NOT * KT];           // static-indexed SSA
    #pragma unroll
    for (int i = 0; i < NOT; ++i)
        #pragma unroll
        for (int kt = 0; kt < KT; ++kt) {
            const size_t we = (size_t)((ot0 + i) * 16 + n16) * LDW + kwoff + kt * 32 + q * 8;
            whr[i * KT + kt] = *(const short8*)(wh + we);
            wlr[i * KT + kt] = *(const short8*)(wl + we);
        }
    #pragma unroll
    for (int i = 0; i < NOT * KT; ++i) { pin(whr[i]); pin(wlr[i]); }
    if constexpr (INIT) {
        #pragma unroll
        for (int i = 0; i < NOT; ++i) {
            const f32x4 binit = *(const f32x4*)(bias + (ot0 + i) * 16 + 4 * q);
            #pragma unroll
            for (int j = 0; j < NPT; ++j) acc[i][j] = binit;
        }
    }
    #pragma unroll
    for (int kt = 0; kt < KT; ++kt) {
        const int k0 = kt * 32 + q * 8;
        short8 bh[NPT], bl[NPT];
        #pragma unroll
        for (int j = 0; j < NPT; ++j) {
            const int p = (pt0t + j) * 16 + n16;
            const int e = p * LDC + (k0 ^ ((p & 7) << 3));
            bh[j] = *(const short8*)(xh + e);
            bl[j] = *(const short8*)(xl + e);
        }
        #pragma unroll
        for (int i = 0; i < NOT; ++i) {
            const short8 ah = whr[i * KT + kt];
            const short8 al = wlr[i * KT + kt];
            #pragma unroll
            for (int j = 0; j < NPT; ++j) acc[i][j] = mfma3(ah, al, bh[j], bl[j], acc[i][j]);
        }
    }
}

// Stage-g with 8 weight frags passed BY VALUE (preloaded+pinned before gather).
template<int NPT, int LDC>
__device__ __forceinline__ void gemm_g(
    const short* __restrict__ xh, const short* __restrict__ xl,
    short8 wh0, short8 wh1, short8 wh2, short8 wh3,
    short8 wl0, short8 wl1, short8 wl2, short8 wl3,
    const float* __restrict__ bias,
    int ot0, int pt0t, int lane, f32x4 (&acc)[1][NPT])
{
    const int q = lane >> 4, n16 = lane & 15;
    const f32x4 binit = *(const f32x4*)(bias + ot0 * 16 + 4 * q);
    #pragma unroll
    for (int j = 0; j < NPT; ++j) acc[0][j] = binit;
    #pragma unroll
    for (int kt = 0; kt < 4; ++kt) {
        const short8 ah = (kt == 0) ? wh0 : (kt == 1) ? wh1 : (kt == 2) ? wh2 : wh3;
        const short8 al = (kt == 0) ? wl0 : (kt == 1) ? wl1 : (kt == 2) ? wl2 : wl3;
        const int k0 = kt * 32 + q * 8;
        short8 bh[NPT], bl[NPT];
        #pragma unroll
        for (int j = 0; j < NPT; ++j) {
            const int p = (pt0t + j) * 16 + n16;
            const int e = p * LDC + (k0 ^ ((p & 7) << 3));
            bh[j] = *(const short8*)(xh + e);
            bl[j] = *(const short8*)(xl + e);
        }
        #pragma unroll
        for (int j = 0; j < NPT; ++j) acc[0][j] = mfma3(ah, al, bh[j], bl[j], acc[0][j]);
    }
}

// GATE: v = base*(1+acc) with base from NF planes; else relu. cvt_pk packing.
template<int NOT, int NPT, bool GATE, int LDCO>
__device__ __forceinline__ void store_act(
    f32x4 (&acc)[NOT][NPT], short* __restrict__ oh, short* __restrict__ ol,
    const short* __restrict__ nfh, const short* __restrict__ nfl,
    int ot0, int pt0t, int lane)
{
    const int q = lane >> 4, n16 = lane & 15;
    #pragma unroll
    for (int i = 0; i < NOT; ++i) {
        const int ob = (ot0 + i) * 16 + 4 * q;
        #pragma unroll
        for (int j = 0; j < NPT; ++j) {
            const int p = (pt0t + j) * 16 + n16;
            const int cs = ob ^ ((p & 7) << 3);
            float v[4];
            if (GATE) {
                const short4 h4 = *(const short4*)(nfh + p * 128 + cs);
                const short4 l4 = *(const short4*)(nfl + p * 128 + cs);
                #pragma unroll
                for (int r = 0; r < 4; ++r) {
                    const float base = bf2f((unsigned short)h4[r]) + bf2f((unsigned short)l4[r]);
                    v[r] = fmaf(base, acc[i][j][r], base);      // base*(1+w)
                }
            } else {
                #pragma unroll
                for (int r = 0; r < 4; ++r) v[r] = fmaxf(acc[i][j][r], 0.f);
            }
            uint2 H, L;
            pack4(v, H, L);
            *(uint2*)(oh + p * LDCO + cs) = H;
            *(uint2*)(ol + p * LDCO + cs) = L;
        }
    }
}

template<bool DENSE>
__global__ __launch_bounds__(512, 2) void pointnet_sa(
    const float* __restrict__ xyz, const float* __restrict__ features,
    const float* __restrict__ new_xyz, const int* __restrict__ idx,
    const short* __restrict__ ws, const short* __restrict__ ftH, const short* __restrict__ ftL,
    const float* __restrict__ bg, const float* __restrict__ b1,
    const float* __restrict__ b2, const float* __restrict__ b3,
    float* __restrict__ out_pooled)  // (B, 256, P)
{
    __shared__ alignas(16) short smem[24576];      // 48 KB
    short* NFh = smem;                              // [64][128]
    short* NFl = smem + 8192;
    short* X0h = smem + 16384;                      // [64][64]
    short* X0l = smem + 20480;
    // X1 = NF cols 0-63 (stride 128); X2P = X0 region (stride 64); X2Q = NF cols 64-127

    const int tid = threadIdx.x, lane = tid & 63, wave = tid >> 6;
    const int q = lane >> 4, n16 = lane & 15;
    const int pt0 = blockIdx.x * 64;
    const int b = pt0 >> 16;

    // ---- preload + PIN stage-g weights BEFORE the gather (latency hides under it) ----
    const int grow = (wave & 3) * 16 + n16;
    const short8 gwh0 = *(const short8*)(ws + WG_HI + grow * 128 + 0 * 32 + q * 8);
    const short8 gwh1 = *(const short8*)(ws + WG_HI + grow * 128 + 1 * 32 + q * 8);
    const short8 gwh2 = *(const short8*)(ws + WG_HI + grow * 128 + 2 * 32 + q * 8);
    const short8 gwh3 = *(const short8*)(ws + WG_HI + grow * 128 + 3 * 32 + q * 8);
    const short8 gwl0 = *(const short8*)(ws + WG_LO + grow * 128 + 0 * 32 + q * 8);
    const short8 gwl1 = *(const short8*)(ws + WG_LO + grow * 128 + 1 * 32 + q * 8);
    const short8 gwl2 = *(const short8*)(ws + WG_LO + grow * 128 + 2 * 32 + q * 8);
    const short8 gwl3 = *(const short8*)(ws + WG_LO + grow * 128 + 3 * 32 + q * 8);
    pin(gwh0); pin(gwh1); pin(gwh2); pin(gwh3);
    pin(gwl0); pin(gwl1); pin(gwl2); pin(gwl3);

    if (DENSE) {
        const int gp = tid >> 3, gc = tid & 7;
        const int pt = pt0 + gp;
        const int n = idx[pt];
        const short* rH = ftH + ((size_t)b * kN + n) * 128;
        const short* rL = ftL + ((size_t)b * kN + n) * 128;
        uint4 hc0 = *(const uint4*)(rH + gc * 8);
        uint4 hc1 = *(const uint4*)(rH + gc * 8 + 64);
        uint4 lc0 = *(const uint4*)(rL + gc * 8);
        uint4 lc1 = *(const uint4*)(rL + gc * 8 + 64);
        if (gc == 0) {
            const float* xp = xyz + ((size_t)b * kN + n) * 3;
            const int pp = (pt >> 5) & (kP - 1);
            const float* np = new_xyz + ((size_t)b * kP + pp) * 3;
            union { uint4 u; short s[8]; } H, L;
            H.u = hc0; L.u = lc0;
            #pragma unroll
            for (int c = 0; c < 3; ++c) {
                const float v = xp[c] - np[c];
                const unsigned short hh = f2bf(v);
                H.s[c] = (short)hh;
                L.s[c] = (short)f2bf(v - bf2f(hh));
            }
            hc0 = H.u; lc0 = L.u;
        }
        const int sw = (gc ^ (gp & 7)) * 8;
        *(uint4*)(NFh + gp * 128 + sw)      = hc0;
        *(uint4*)(NFh + gp * 128 + sw + 64) = hc1;
        *(uint4*)(NFl + gp * 128 + sw)      = lc0;
        *(uint4*)(NFl + gp * 128 + sw + 64) = lc1;
    } else {
        const int p = tid & 63;
        const int cg = tid >> 6;
        const int pt = pt0 + p;
        const int n = idx[pt];
        const int pp = (pt >> 5) & (kP - 1);
        const float* fbp = features + (size_t)b * kC * kN + n;
        const float* xp = xyz + ((size_t)b * kN + n) * 3;
        const float* np = new_xyz + ((size_t)b * kP + pp) * 3;
        for (int c = cg; c < 128; c += 8) {
            float v;
            if (c < 3)        v = xp[c] - np[c];
            else if (c < 106) v = fbp[(size_t)(c - 3) * kN];
            else              v = 0.f;
            const unsigned short h = f2bf(v);
            const int cs = c ^ ((p & 7) << 3);
            NFh[p * 128 + cs] = (short)h;
            NFl[p * 128 + cs] = (short)f2bf(v - bf2f(h));
        }
    }
    __syncthreads();

    // ---- stage g (weights already in registers) ----
    {
        f32x4 a[1][2];
        gemm_g<2, 128>(NFh, NFl, gwh0, gwh1, gwh2, gwh3, gwl0, gwl1, gwl2, gwl3,
                       bg, wave & 3, 2 * (wave >> 2), lane, a);
        store_act<1, 2, true, 64>(a, X0h, X0l, NFh, NFl, wave & 3, 2 * (wave >> 2), lane);
    }
    __syncthreads();                               // B1: NF dead

    // ---- stage 1 -> X1 in NF cols 0-63 ----
    {
        f32x4 a[1][2];
        gemm_core<1, 2, 2, 64, 64, true>(X0h, X0l, ws + W1_HI, ws + W1_LO, b1, 0,
                                         wave & 3, 2 * (wave >> 2), lane, a);
        store_act<1, 2, false, 128>(a, NFh, NFl, nullptr, nullptr,
                                    wave & 3, 2 * (wave >> 2), lane);
    }
    __syncthreads();                               // B2: X0 dead

    // ---- stage 2 -> X2 split ----
    {
        f32x4 a[2][2];
        gemm_core<2, 2, 2, 128, 64, true>(NFh, NFl, ws + W2_HI, ws + W2_LO, b2, 0,
                                          2 * (wave & 3), 2 * (wave >> 2), lane, a);
        if ((wave & 3) < 2)
            store_act<2, 2, false, 64>(a, X0h, X0l, nullptr, nullptr,
                                       2 * (wave & 3), 2 * (wave >> 2), lane);
        else
            store_act<2, 2, false, 128>(a, NFh + 64, NFl + 64, nullptr, nullptr,
                                        (2 * (wave & 3)) & 3, 2 * (wave >> 2), lane);
    }
    __syncthreads();                               // B3

    // ---- stage 3: K over X2P then X2Q + pool ----
    {
        f32x4 a[2][4];
        gemm_core<2, 4, 2, 64, 128, true >(X0h, X0l, ws + W3_HI, ws + W3_LO, b3, 0,
                                           2 * wave, 0, lane, a);
        gemm_core<2, 4, 2, 128, 128, false>(NFh + 64, NFl + 64, ws + W3_HI, ws + W3_LO,
                                            nullptr, 64, 2 * wave, 0, lane, a);
        #pragma unroll
        for (int i = 0; i < 2; ++i) {
            #pragma unroll
            for (int sg = 0; sg < 2; ++sg) {
                #pragma unroll
                for (int r = 0; r < 4; ++r) {
                    float v = fmaxf(a[i][2 * sg][r], a[i][2 * sg + 1][r]);
                    v = fmaxf(v, __shfl_xor(v, 1, 16));
                    v = fmaxf(v, __shfl_xor(v, 2, 16));
                    v = fmaxf(v, __shfl_xor(v, 4, 16));
                    v = fmaxf(v, __shfl_xor(v, 8, 16));
                    v = fmaxf(v, 0.f);
                    if (n16 == 0) {
                        const int o = (2 * wave + i) * 16 + 4 * q + r;
                        const int g = (pt0 >> 5) + sg;
                        out_pooled[((size_t)(g >> 11) * 256 + o) * kP + (g & (kP - 1))] = v;
                    }
                }
            }
        }
    }
}
}  // namespace

extern "C" void kernel_launch(void* const* d_in, const int* in_sizes, int n_in,
                              void* d_out, int out_size, void* d_ws, size_t ws_size,
                              hipStream_t stream) {
    const float* xyz      = (const float*)d_in[0];
    const float* features = (const float*)d_in[1];
    const float* new_xyz  = (const float*)d_in[2];
    const int*   idx      = (const int*)d_in[3];
    const float* Wg = (const float*)d_in[4];
    const float* bg = (const float*)d_in[5];
    const float* W1 = (const float*)d_in[6];
    const float* b1 = (const float*)d_in[7];
    const float* W2 = (const float*)d_in[8];
    const float* b2 = (const float*)d_in[9];
    const float* W3 = (const float*)d_in[10];
    const float* b3 = (const float*)d_in[11];
    float* out = (float*)d_out;
    short* ws  = (short*)d_ws;
    short* ftH = (short*)((char*)d_ws + FT_OFF);
    short* ftL = ftH + FT_SHORTS;

    const int nxyz = kB * kP * 3;
    copy_newxyz<<<(nxyz + 255) / 256, 256, 0, stream>>>(new_xyz, out, nxyz);
    prep_weights<<<(53248 + 255) / 256, 256, 0, stream>>>(Wg, W1, W2, W3, ws);

    float* pooled = out + nxyz;
    if (ws_size >= WS_NEED) {
        prep_feat<<<kB * (kN / 64), 512, 0, stream>>>(features, ftH, ftL);
        pointnet_sa<true><<<(kB * kP * kS) / 64, 512, 0, stream>>>(
            xyz, features, new_xyz, idx, ws, ftH, ftL, bg, b1, b2, b3, pooled);
    } else {
        pointnet_sa<false><<<(kB * kP * kS) / 64, 512, 0, stream>>>(
            xyz, features, new_xyz, idx, ws, nullptr, nullptr, bg, b1, b2, b3, pooled);
    }
}